// Round 11
// baseline (82.530 us; speedup 1.0000x reference)
//
#include <hip/hip_runtime.h>

#define N_NODES 100000
#define DIM 64
#define N_TILES (N_NODES / 16)   // 6250 row-tiles of 16

#define BSHIFT 7
#define BN 128                         // nodes per bucket
#define NB ((N_NODES + BN - 1) / BN)   // 782 buckets
#define BC 2048                        // bucket capacity (avg 1600, ~11 sigma)

#define PB 128                         // partition blocks
#define TB 384                         // transform blocks

using bf16x8 = __attribute__((ext_vector_type(8))) short;
using f32x4  = __attribute__((ext_vector_type(4))) float;

// ---- f32 -> bf16 (round-to-nearest-even) -------------------------------

__device__ __forceinline__ unsigned short f2bf(float f) {
    unsigned u = __float_as_uint(f);
    unsigned r = u + 0x7FFFu + ((u >> 16) & 1u);
    return (unsigned short)(r >> 16);
}

union PrepShared {
    struct { int hist[NB]; int gb[NB]; int loff[NB]; } p;   // 9.4 KB
    ushort t[4 * 16 * 72];                                  // 9.2 KB
};

// ---- fused pass 1: partition (blocks 0..PB) + transform (PB..PB+TB) ----
__global__ void prep_kernel(const float* __restrict__ x,
                            const float* __restrict__ W,
                            const int* __restrict__ edge_src,
                            const int* __restrict__ edge_dst,
                            int* __restrict__ gcur,
                            unsigned* __restrict__ buckets,
                            ushort* __restrict__ y, int E) {
    __shared__ PrepShared sh;
    const int tid = threadIdx.x;

    if (blockIdx.x < PB) {
        // ---------- partition: 2-pass over this block's edge range ------
        const int per = (E + PB - 1) / PB;
        const int e0 = blockIdx.x * per;
        int e1 = e0 + per; if (e1 > E) e1 = E;

        for (int i = tid; i < NB; i += blockDim.x) sh.p.hist[i] = 0;
        __syncthreads();

        for (int e = e0 + tid; e < e1; e += blockDim.x)
            atomicAdd(&sh.p.hist[edge_dst[e] >> BSHIFT], 1);
        __syncthreads();

        for (int b = tid; b < NB; b += blockDim.x) {
            int c = sh.p.hist[b];
            sh.p.loff[b] = 0;
            if (c > 0) sh.p.gb[b] = atomicAdd(&gcur[b], c);
        }
        __syncthreads();

        for (int e = e0 + tid; e < e1; e += blockDim.x) {
            int d = edge_dst[e];
            int s = edge_src[e];
            int b = d >> BSHIFT;
            int pos = sh.p.gb[b] + atomicAdd(&sh.p.loff[b], 1);
            if (pos < BC)
                buckets[(size_t)b * BC + pos] =
                    ((unsigned)(d & (BN - 1)) << 20) | (unsigned)s;
        }
    } else {
        // ---------- transform: y = bf16(x @ W), MFMA -------------------
        const int lane = tid & 63;
        const int w    = tid >> 6;
        const int l15  = lane & 15;
        const int l4   = lane >> 4;
        const int tb   = blockIdx.x - PB;

        if (tb == 0 && tid < 8)   // zero row at index N_NODES
            ((uint4*)(y + (size_t)N_NODES * DIM))[tid] = make_uint4(0, 0, 0, 0);

        bf16x8 bfrag[4][2];
#pragma unroll
        for (int ct = 0; ct < 4; ++ct)
#pragma unroll
            for (int kt = 0; kt < 2; ++kt)
#pragma unroll
                for (int j = 0; j < 8; ++j) {
                    int k = kt * 32 + l4 * 8 + j;
                    int c = ct * 16 + l15;
                    bfrag[ct][kt][j] = (short)f2bf(W[k * DIM + c]);
                }

        ushort* myl = sh.t + w * (16 * 72);
        const int gw = tb * 4 + w;
        const int nw = TB * 4;

        for (int rt = gw; rt < N_TILES; rt += nw) {
            const float* xt = x + (size_t)rt * 16 * DIM;

            f32x4 zero = {0.f, 0.f, 0.f, 0.f};
            f32x4 acc0 = zero, acc1 = zero, acc2 = zero, acc3 = zero;
#pragma unroll
            for (int kt = 0; kt < 2; ++kt) {
                const float* ap = xt + (size_t)l15 * DIM + kt * 32 + l4 * 8;
                float4 p0 = *(const float4*)(ap);
                float4 p1 = *(const float4*)(ap + 4);
                bf16x8 afrag;
                afrag[0] = (short)f2bf(p0.x); afrag[1] = (short)f2bf(p0.y);
                afrag[2] = (short)f2bf(p0.z); afrag[3] = (short)f2bf(p0.w);
                afrag[4] = (short)f2bf(p1.x); afrag[5] = (short)f2bf(p1.y);
                afrag[6] = (short)f2bf(p1.z); afrag[7] = (short)f2bf(p1.w);
                acc0 = __builtin_amdgcn_mfma_f32_16x16x32_bf16(afrag, bfrag[0][kt], acc0, 0, 0, 0);
                acc1 = __builtin_amdgcn_mfma_f32_16x16x32_bf16(afrag, bfrag[1][kt], acc1, 0, 0, 0);
                acc2 = __builtin_amdgcn_mfma_f32_16x16x32_bf16(afrag, bfrag[2][kt], acc2, 0, 0, 0);
                acc3 = __builtin_amdgcn_mfma_f32_16x16x32_bf16(afrag, bfrag[3][kt], acc3, 0, 0, 0);
            }

#pragma unroll
            for (int r = 0; r < 4; ++r) {
                int m = l4 * 4 + r;
                myl[m * 72 +  0 + l15] = f2bf(acc0[r]);
                myl[m * 72 + 16 + l15] = f2bf(acc1[r]);
                myl[m * 72 + 32 + l15] = f2bf(acc2[r]);
                myl[m * 72 + 48 + l15] = f2bf(acc3[r]);
            }
            int rr = lane >> 2, q = lane & 3;
            const uint4* src = (const uint4*)(myl + rr * 72 + q * 16);
            uint4 d0 = src[0];
            uint4 d1 = src[1];
            ushort* dst = y + ((size_t)(rt * 16 + rr)) * DIM + q * 16;
            *(uint4*)(dst)     = d0;
            *(uint4*)(dst + 8) = d1;
        }
    }
}

// ---- pass 2: per-bucket counting sort + register-accumulated gather ----
__global__ void sort_gather_kernel(const ushort* __restrict__ y,
                                   const int* __restrict__ gcur,
                                   const unsigned* __restrict__ buckets,
                                   const float* __restrict__ bias,
                                   float* __restrict__ out) {
    __shared__ unsigned vals[BC];      // 8 KB staged entries
    __shared__ unsigned sorted[BC];    // 8 KB sorted src indices
    __shared__ int h[BN];
    __shared__ int tmp[BN];
    __shared__ int offs[BN + 1];
    __shared__ int cur[BN];

    const int tid = threadIdx.x;
    const int b = blockIdx.x;

    int cnt = gcur[b];
    if (cnt > BC) cnt = BC;

    for (int i = tid; i < BN; i += blockDim.x) h[i] = 0;
    __syncthreads();

    const unsigned* __restrict__ bk = buckets + (size_t)b * BC;
    for (int i = tid; i < cnt; i += blockDim.x) {
        unsigned v = bk[i];
        vals[i] = v;
        atomicAdd(&h[v >> 20], 1);
    }
    __syncthreads();

    if (tid < BN) tmp[tid] = h[tid];
    __syncthreads();
    for (int o = 1; o < BN; o <<= 1) {
        int t = 0;
        if (tid < BN && tid >= o) t = tmp[tid - o];
        __syncthreads();
        if (tid < BN) tmp[tid] += t;
        __syncthreads();
    }
    if (tid < BN) {
        int e = tmp[tid] - h[tid];       // exclusive
        offs[tid] = e;
        cur[tid] = e;
    }
    if (tid == 0) offs[BN] = cnt;
    __syncthreads();

    for (int i = tid; i < cnt; i += blockDim.x) {
        unsigned v = vals[i];
        int dl = v >> 20;
        int pos = atomicAdd(&cur[dl], 1);
        sorted[pos] = v & 0xFFFFFu;
    }
    __syncthreads();

    const int grp = tid >> 4;        // 16 groups of 16 lanes
    const int f = tid & 15;
    const uint2* __restrict__ y2 = (const uint2*)y;
    const int node0 = b * BN;
    float4 bb = ((const float4*)bias)[f];

    for (int r = grp; r < BN; r += 16) {
        int nd = node0 + r;
        if (nd >= N_NODES) break;
        int s0i = offs[r], e0i = offs[r + 1];
        float a0 = 0.f, a1 = 0.f, a2 = 0.f, a3 = 0.f;
        for (int i = s0i; i < e0i; i += 8) {
            int idx[8];
#pragma unroll
            for (int k = 0; k < 8; ++k)
                idx[k] = (i + k < e0i) ? (int)sorted[i + k] : N_NODES;
#pragma unroll
            for (int k = 0; k < 8; ++k) {
                uint2 v = y2[(size_t)idx[k] * 16 + f];
                a0 += __uint_as_float(v.x << 16);
                a1 += __uint_as_float(v.x & 0xffff0000u);
                a2 += __uint_as_float(v.y << 16);
                a3 += __uint_as_float(v.y & 0xffff0000u);
            }
        }
        float4 o;
        o.x = a0 + bb.x; o.y = a1 + bb.y; o.z = a2 + bb.z; o.w = a3 + bb.w;
        *(float4*)(out + (size_t)nd * DIM + f * 4) = o;
    }
}

// ---- Launch ------------------------------------------------------------

extern "C" void kernel_launch(void* const* d_in, const int* in_sizes, int n_in,
                              void* d_out, int out_size, void* d_ws, size_t ws_size,
                              hipStream_t stream) {
    const float* x        = (const float*)d_in[0];
    const int*   edge_src = (const int*)d_in[1];
    const int*   edge_dst = (const int*)d_in[2];
    const float* W        = (const float*)d_in[3];
    const float* b        = (const float*)d_in[4];
    float* out = (float*)d_out;

    const int E = in_sizes[1];

    // ws layout: y[(N+1)*64] bf16 (12.8 MB) | gcur[NB] | buckets[NB*BC] (6.4 MB)
    ushort*   y       = (ushort*)d_ws;
    int*      gcur    = (int*)(y + (size_t)(N_NODES + 1) * DIM);
    unsigned* buckets = (unsigned*)(gcur + NB);

    hipMemsetAsync(gcur, 0, NB * sizeof(int), stream);

    prep_kernel<<<PB + TB, 256, 0, stream>>>(x, W, edge_src, edge_dst,
                                             gcur, buckets, y, E);
    sort_gather_kernel<<<NB, 256, 0, stream>>>(y, gcur, buckets, b, out);
}

// Round 12
// 63.123 us; speedup vs baseline: 1.3075x; 1.3075x over previous
//
#include <hip/hip_runtime.h>

#define N_NODES 100000
#define DIM 64
#define N_TILES (N_NODES / 16)   // 6250 row-tiles of 16

#define BSHIFT 7
#define BN 128                         // nodes per bucket
#define NB ((N_NODES + BN - 1) / BN)   // 782 buckets
#define BC 2048                        // bucket capacity (avg 1600, ~11 sigma)

#define NP 256                         // partition chunks (even blocks)
#define NT 256                         // transform blocks (odd blocks)
#define CHUNK_P 4928                   // max edges per partition chunk

using bf16x8 = __attribute__((ext_vector_type(8))) short;
using f32x4  = __attribute__((ext_vector_type(4))) float;

// ---- f32 -> bf16 (round-to-nearest-even) -------------------------------

__device__ __forceinline__ unsigned short f2bf(float f) {
    unsigned u = __float_as_uint(f);
    unsigned r = u + 0x7FFFu + ((u >> 16) & 1u);
    return (unsigned short)(r >> 16);
}

union PrepShared {
    struct {
        unsigned vals[CHUNK_P];        // 19.7 KB packed entries
        unsigned short bkt[CHUNK_P];   // 9.9 KB bucket ids
        int hist[NB];                  // 3.1 KB
        int gb[NB];
        int loff[NB];
    } p;                               // ~39 KB
    ushort t[16 * 16 * 72];            // 36.9 KB (16 waves x tile)
};

// ---- fused pass 1: even blocks partition, odd blocks transform ---------
__global__ __launch_bounds__(1024, 2)
void prep_kernel(const float* __restrict__ x,
                 const float* __restrict__ W,
                 const int* __restrict__ edge_src,
                 const int* __restrict__ edge_dst,
                 int* __restrict__ gcur,
                 unsigned* __restrict__ buckets,
                 ushort* __restrict__ y, int E) {
    __shared__ PrepShared sh;
    const int tid = threadIdx.x;

    if ((blockIdx.x & 1) == 0) {
        // ---------- partition: LDS-staged chunk, one range claim/bucket --
        const int pid = blockIdx.x >> 1;
        const int per = (E + NP - 1) / NP;
        const int e0 = pid * per;
        int e1 = e0 + per; if (e1 > E) e1 = E;

        for (int base = e0; base < e1; base += CHUNK_P) {
            int m = e1 - base; if (m > CHUNK_P) m = CHUNK_P;

            for (int i = tid; i < NB; i += blockDim.x) sh.p.hist[i] = 0;
            __syncthreads();

            for (int i = tid; i < m; i += blockDim.x) {
                int d = edge_dst[base + i];
                int s = edge_src[base + i];
                int b = d >> BSHIFT;
                sh.p.vals[i] = ((unsigned)(d & (BN - 1)) << 20) | (unsigned)s;
                sh.p.bkt[i] = (unsigned short)b;
                atomicAdd(&sh.p.hist[b], 1);
            }
            __syncthreads();

            for (int b = tid; b < NB; b += blockDim.x) {
                int c = sh.p.hist[b];
                sh.p.loff[b] = 0;
                if (c > 0) sh.p.gb[b] = atomicAdd(&gcur[b], c);
            }
            __syncthreads();

            for (int i = tid; i < m; i += blockDim.x) {
                int b = sh.p.bkt[i];
                int pos = sh.p.gb[b] + atomicAdd(&sh.p.loff[b], 1);
                if (pos < BC) buckets[(size_t)b * BC + pos] = sh.p.vals[i];
            }
            __syncthreads();
        }
    } else {
        // ---------- transform: y = bf16(x @ W), MFMA, 16 waves ----------
        const int lane = tid & 63;
        const int w    = tid >> 6;            // 0..15
        const int l15  = lane & 15;
        const int l4   = lane >> 4;
        const int tb   = blockIdx.x >> 1;

        if (tb == 0 && tid < 8)   // zero row at index N_NODES
            ((uint4*)(y + (size_t)N_NODES * DIM))[tid] = make_uint4(0, 0, 0, 0);

        bf16x8 bfrag[4][2];
#pragma unroll
        for (int ct = 0; ct < 4; ++ct)
#pragma unroll
            for (int kt = 0; kt < 2; ++kt)
#pragma unroll
                for (int j = 0; j < 8; ++j) {
                    int k = kt * 32 + l4 * 8 + j;
                    int c = ct * 16 + l15;
                    bfrag[ct][kt][j] = (short)f2bf(W[k * DIM + c]);
                }

        ushort* myl = sh.t + w * (16 * 72);
        const int gw = tb * 16 + w;
        const int nw = NT * 16;               // 4096 waves

        for (int rt = gw; rt < N_TILES; rt += nw) {
            const float* xt = x + (size_t)rt * 16 * DIM;

            f32x4 zero = {0.f, 0.f, 0.f, 0.f};
            f32x4 acc0 = zero, acc1 = zero, acc2 = zero, acc3 = zero;
#pragma unroll
            for (int kt = 0; kt < 2; ++kt) {
                const float* ap = xt + (size_t)l15 * DIM + kt * 32 + l4 * 8;
                float4 p0 = *(const float4*)(ap);
                float4 p1 = *(const float4*)(ap + 4);
                bf16x8 afrag;
                afrag[0] = (short)f2bf(p0.x); afrag[1] = (short)f2bf(p0.y);
                afrag[2] = (short)f2bf(p0.z); afrag[3] = (short)f2bf(p0.w);
                afrag[4] = (short)f2bf(p1.x); afrag[5] = (short)f2bf(p1.y);
                afrag[6] = (short)f2bf(p1.z); afrag[7] = (short)f2bf(p1.w);
                acc0 = __builtin_amdgcn_mfma_f32_16x16x32_bf16(afrag, bfrag[0][kt], acc0, 0, 0, 0);
                acc1 = __builtin_amdgcn_mfma_f32_16x16x32_bf16(afrag, bfrag[1][kt], acc1, 0, 0, 0);
                acc2 = __builtin_amdgcn_mfma_f32_16x16x32_bf16(afrag, bfrag[2][kt], acc2, 0, 0, 0);
                acc3 = __builtin_amdgcn_mfma_f32_16x16x32_bf16(afrag, bfrag[3][kt], acc3, 0, 0, 0);
            }

#pragma unroll
            for (int r = 0; r < 4; ++r) {
                int m = l4 * 4 + r;
                myl[m * 72 +  0 + l15] = f2bf(acc0[r]);
                myl[m * 72 + 16 + l15] = f2bf(acc1[r]);
                myl[m * 72 + 32 + l15] = f2bf(acc2[r]);
                myl[m * 72 + 48 + l15] = f2bf(acc3[r]);
            }
            int rr = lane >> 2, q = lane & 3;
            const uint4* src = (const uint4*)(myl + rr * 72 + q * 16);
            uint4 d0 = src[0];
            uint4 d1 = src[1];
            ushort* dst = y + ((size_t)(rt * 16 + rr)) * DIM + q * 16;
            *(uint4*)(dst)     = d0;
            *(uint4*)(dst + 8) = d1;
        }
    }
}

// ---- pass 2: per-bucket counting sort + register-accumulated gather ----
__global__ void sort_gather_kernel(const ushort* __restrict__ y,
                                   const int* __restrict__ gcur,
                                   const unsigned* __restrict__ buckets,
                                   const float* __restrict__ bias,
                                   float* __restrict__ out) {
    __shared__ unsigned vals[BC];      // 8 KB staged entries
    __shared__ unsigned sorted[BC];    // 8 KB sorted src indices
    __shared__ int h[BN];
    __shared__ int tmp[BN];
    __shared__ int offs[BN + 1];
    __shared__ int cur[BN];

    const int tid = threadIdx.x;
    const int b = blockIdx.x;

    int cnt = gcur[b];
    if (cnt > BC) cnt = BC;

    for (int i = tid; i < BN; i += blockDim.x) h[i] = 0;
    __syncthreads();

    const unsigned* __restrict__ bk = buckets + (size_t)b * BC;
    for (int i = tid; i < cnt; i += blockDim.x) {
        unsigned v = bk[i];
        vals[i] = v;
        atomicAdd(&h[v >> 20], 1);
    }
    __syncthreads();

    if (tid < BN) tmp[tid] = h[tid];
    __syncthreads();
    for (int o = 1; o < BN; o <<= 1) {
        int t = 0;
        if (tid < BN && tid >= o) t = tmp[tid - o];
        __syncthreads();
        if (tid < BN) tmp[tid] += t;
        __syncthreads();
    }
    if (tid < BN) {
        int e = tmp[tid] - h[tid];       // exclusive
        offs[tid] = e;
        cur[tid] = e;
    }
    if (tid == 0) offs[BN] = cnt;
    __syncthreads();

    for (int i = tid; i < cnt; i += blockDim.x) {
        unsigned v = vals[i];
        int dl = v >> 20;
        int pos = atomicAdd(&cur[dl], 1);
        sorted[pos] = v & 0xFFFFFu;
    }
    __syncthreads();

    const int grp = tid >> 4;        // 16 groups of 16 lanes
    const int f = tid & 15;
    const uint2* __restrict__ y2 = (const uint2*)y;
    const int node0 = b * BN;
    float4 bb = ((const float4*)bias)[f];

    for (int r = grp; r < BN; r += 16) {
        int nd = node0 + r;
        if (nd >= N_NODES) break;
        int s0i = offs[r], e0i = offs[r + 1];
        float a0 = 0.f, a1 = 0.f, a2 = 0.f, a3 = 0.f;
        for (int i = s0i; i < e0i; i += 8) {
            int idx[8];
#pragma unroll
            for (int k = 0; k < 8; ++k)
                idx[k] = (i + k < e0i) ? (int)sorted[i + k] : N_NODES;
#pragma unroll
            for (int k = 0; k < 8; ++k) {
                uint2 v = y2[(size_t)idx[k] * 16 + f];
                a0 += __uint_as_float(v.x << 16);
                a1 += __uint_as_float(v.x & 0xffff0000u);
                a2 += __uint_as_float(v.y << 16);
                a3 += __uint_as_float(v.y & 0xffff0000u);
            }
        }
        float4 o;
        o.x = a0 + bb.x; o.y = a1 + bb.y; o.z = a2 + bb.z; o.w = a3 + bb.w;
        *(float4*)(out + (size_t)nd * DIM + f * 4) = o;
    }
}

// ---- Launch ------------------------------------------------------------

extern "C" void kernel_launch(void* const* d_in, const int* in_sizes, int n_in,
                              void* d_out, int out_size, void* d_ws, size_t ws_size,
                              hipStream_t stream) {
    const float* x        = (const float*)d_in[0];
    const int*   edge_src = (const int*)d_in[1];
    const int*   edge_dst = (const int*)d_in[2];
    const float* W        = (const float*)d_in[3];
    const float* b        = (const float*)d_in[4];
    float* out = (float*)d_out;

    const int E = in_sizes[1];

    // ws layout: y[(N+1)*64] bf16 (12.8 MB) | gcur[NB] | buckets[NB*BC] (6.4 MB)
    ushort*   y       = (ushort*)d_ws;
    int*      gcur    = (int*)(y + (size_t)(N_NODES + 1) * DIM);
    unsigned* buckets = (unsigned*)(gcur + NB);

    hipMemsetAsync(gcur, 0, NB * sizeof(int), stream);

    prep_kernel<<<NP + NT, 1024, 0, stream>>>(x, W, edge_src, edge_dst,
                                              gcur, buckets, y, E);
    sort_gather_kernel<<<NB, 256, 0, stream>>>(y, gcur, buckets, b, out);
}